// Round 1
// baseline (490.089 us; speedup 1.0000x reference)
//
#include <hip/hip_runtime.h>
#include <hip/hip_bf16.h>
#include <stdint.h>

#define NTOK 65536
#define DIM 512
#define NEXP 4

using u16 = unsigned short;
using u32 = unsigned int;
typedef __attribute__((ext_vector_type(4))) float f32x4;
typedef __attribute__((ext_vector_type(8))) short bf16x8;
typedef __attribute__((ext_vector_type(8))) u16 u16x8;

__device__ __forceinline__ u16 f2bf(float f) {
  u32 u = __builtin_bit_cast(u32, f);
  u32 r = (u + 0x7FFFu + ((u >> 16) & 1u)) >> 16;
  return (u16)r;
}

#define GLOAD_LDS16(gp, lp)                                                    \
  __builtin_amdgcn_global_load_lds(                                            \
      (const __attribute__((address_space(1))) void*)(gp),                     \
      (__attribute__((address_space(3))) void*)(lp), 16, 0, 0)

// ---------------- K0: weight transpose + fp32->bf16 ----------------
// dst[mat][h][d] = bf16(src[mat][d][h])   (N-major so MFMA B-frags are contiguous)
__global__ void wconv(const float* __restrict__ src, u16* __restrict__ dst) {
  __shared__ float tile[32][33];
  int mat = blockIdx.y;
  int tx = blockIdx.x & 15, ty = blockIdx.x >> 4;
  const float* s = src + (size_t)mat * DIM * DIM;
  u16* d = dst + (size_t)mat * DIM * DIM;
  int lx = threadIdx.x & 31, ly0 = threadIdx.x >> 5;
#pragma unroll
  for (int i = 0; i < 4; ++i) {
    int ly = ly0 + i * 8;
    tile[ly][lx] = s[(size_t)(ty * 32 + ly) * DIM + tx * 32 + lx];
  }
  __syncthreads();
#pragma unroll
  for (int i = 0; i < 4; ++i) {
    int ly = ly0 + i * 8;
    d[(size_t)(tx * 32 + ly) * DIM + ty * 32 + lx] = f2bf(tile[lx][ly]);
  }
}

// ---------------- K1: router (fp32) + x -> bf16 ----------------
// one wave per token; wmaskT[e][t] dense (zeros for unselected experts)
__global__ void router_kernel(const float* __restrict__ x, const float* __restrict__ rw,
                              const float* __restrict__ rb, u16* __restrict__ xb,
                              float* __restrict__ wmaskT) {
  int lane = threadIdx.x & 63, wave = threadIdx.x >> 6;
  size_t t = (size_t)blockIdx.x * 4 + wave;
  const float* xr = x + t * DIM + lane * 8;
  f32x4 v0 = *(const f32x4*)xr;
  f32x4 v1 = *(const f32x4*)(xr + 4);
  float l0 = 0.f, l1 = 0.f, l2 = 0.f, l3 = 0.f;
  const float* rwp = rw + (size_t)lane * 32;  // 8 rows x 4 experts
#pragma unroll
  for (int j = 0; j < 8; ++j) {
    float xv = (j < 4) ? v0[j] : v1[j - 4];
    f32x4 r = *(const f32x4*)(rwp + j * 4);
    l0 += xv * r[0]; l1 += xv * r[1]; l2 += xv * r[2]; l3 += xv * r[3];
  }
#pragma unroll
  for (int off = 32; off; off >>= 1) {
    l0 += __shfl_xor(l0, off); l1 += __shfl_xor(l1, off);
    l2 += __shfl_xor(l2, off); l3 += __shfl_xor(l3, off);
  }
  float lv[4] = {l0 + rb[0], l1 + rb[1], l2 + rb[2], l3 + rb[3]};
  int i0 = 0; float b0 = lv[0];
#pragma unroll
  for (int e = 1; e < 4; ++e) if (lv[e] > b0) { b0 = lv[e]; i0 = e; }
  int i1 = (i0 == 0) ? 1 : 0; float b1 = lv[i1];
#pragma unroll
  for (int e = 0; e < 4; ++e) if (e != i0 && lv[e] > b1) { b1 = lv[e]; i1 = e; }
  float ex = __expf(b1 - b0);
  float w0 = 1.0f / (1.0f + ex);
  float w1 = ex * w0;
  if (lane < 4) {
    float wv = (lane == i0) ? w0 : ((lane == i1) ? w1 : 0.0f);
    wmaskT[(size_t)lane * NTOK + t] = wv;
  }
  u16x8 o;
#pragma unroll
  for (int j = 0; j < 4; ++j) { o[j] = f2bf(v0[j]); o[4 + j] = f2bf(v1[j]); }
  *(u16x8*)(xb + t * DIM + lane * 8) = o;
}

// ---------------- shared GEMM helpers ----------------
// stage a 128x64 bf16 tile (row stride DIM) into linear LDS [128][64]
__device__ __forceinline__ void stage_tile(const u16* g, u16* lds, int wave, int lane) {
  int rl = lane >> 3;
  int kb = (lane & 7) * 8;
#pragma unroll
  for (int j = 0; j < 4; ++j) {
    int row = wave * 32 + j * 8;  // wave-uniform LDS base; HW adds lane*16B
    GLOAD_LDS16(g + (size_t)(row + rl) * DIM + kb, lds + row * 64);
  }
}

// one BK=64 step: 16 ds_read_b128 + 32 MFMA per wave (64x64 wave tile)
__device__ __forceinline__ void gemm_step(const u16* As, const u16* Bs, int lane,
                                          int wy, int wx, f32x4 acc[4][4]) {
  int r = lane & 15, kof = (lane >> 4) * 8;
#pragma unroll
  for (int kc = 0; kc < 2; ++kc) {
    bf16x8 a[4], b[4];
#pragma unroll
    for (int i = 0; i < 4; ++i)
      a[i] = *(const bf16x8*)(As + (wy * 64 + i * 16 + r) * 64 + kc * 32 + kof);
#pragma unroll
    for (int i = 0; i < 4; ++i)
      b[i] = *(const bf16x8*)(Bs + (wx * 64 + i * 16 + r) * 64 + kc * 32 + kof);
#pragma unroll
    for (int i = 0; i < 4; ++i)
#pragma unroll
      for (int j = 0; j < 4; ++j)
        acc[i][j] = __builtin_amdgcn_mfma_f32_16x16x32_bf16(a[i], b[j], acc[i][j], 0, 0, 0);
  }
}

// ---------------- K2: dense expert GEMM + SiLU + weighted combine ----------------
__global__ __launch_bounds__(256, 2) void expert_gemm(
    const u16* __restrict__ xb, const u16* __restrict__ ewt,
    const float* __restrict__ eb, const float* __restrict__ wmaskT,
    u16* __restrict__ comb) {
  __shared__ u16 As[2][128 * 64];
  __shared__ u16 Bs[2][128 * 64];
  int tid = threadIdx.x, lane = tid & 63, wave = tid >> 6;
  int wy = wave >> 1, wx = wave & 1;
  int m0 = blockIdx.x * 128, n0 = blockIdx.y * 128;
  f32x4 acc[4][4], comba[4][4];
#pragma unroll
  for (int i = 0; i < 4; ++i)
#pragma unroll
    for (int j = 0; j < 4; ++j) { acc[i][j] = (f32x4)(0.f); comba[i][j] = (f32x4)(0.f); }

  const u16* agbase = xb + (size_t)m0 * DIM;
  stage_tile(agbase, As[0], wave, lane);
  stage_tile(ewt + (size_t)n0 * DIM, Bs[0], wave, lane);
  __syncthreads();

#pragma unroll 1
  for (int it = 0; it < 32; ++it) {
    int cur = it & 1;
    int nxt = it + 1;
    if (nxt < 32) {  // issue next-tile loads BEFORE compute (T3 minimum 2-phase)
      int e = nxt >> 3, ks = nxt & 7;
      stage_tile(agbase + ks * 64, As[cur ^ 1], wave, lane);
      stage_tile(ewt + (size_t)e * DIM * DIM + (size_t)n0 * DIM + ks * 64, Bs[cur ^ 1], wave, lane);
    }
    gemm_step(As[cur], Bs[cur], lane, wy, wx, acc);
    if ((it & 7) == 7) {  // per-expert epilogue: bias + SiLU + mask-weight
      int e = it >> 3;
#pragma unroll
      for (int i = 0; i < 4; ++i) {
        int tb = m0 + wy * 64 + i * 16 + ((lane >> 4) << 2);
        float wv[4];
#pragma unroll
        for (int rr = 0; rr < 4; ++rr) wv[rr] = wmaskT[(size_t)e * NTOK + tb + rr];
#pragma unroll
        for (int j = 0; j < 4; ++j) {
          int h = n0 + wx * 64 + j * 16 + (lane & 15);
          float bias = eb[e * DIM + h];
#pragma unroll
          for (int rr = 0; rr < 4; ++rr) {
            float z = acc[i][j][rr] + bias;
            float sg = 1.0f / (1.0f + __expf(-z));
            comba[i][j][rr] += wv[rr] * (z * sg);
            acc[i][j][rr] = 0.0f;
          }
        }
      }
    }
    __syncthreads();  // drains this wave's global_load_lds (vmcnt0) + barrier
  }
#pragma unroll
  for (int i = 0; i < 4; ++i) {
    int tb = m0 + wy * 64 + i * 16 + ((lane >> 4) << 2);
#pragma unroll
    for (int j = 0; j < 4; ++j) {
      int h = n0 + wx * 64 + j * 16 + (lane & 15);
#pragma unroll
      for (int rr = 0; rr < 4; ++rr)
        comb[(size_t)(tb + rr) * DIM + h] = f2bf(comba[i][j][rr]);
    }
  }
}

// ---------------- K3: out-proj GEMM + bias + fp32 residual -> y (in d_out) ----------------
__global__ __launch_bounds__(256, 2) void out_gemm(
    const u16* __restrict__ comb, const u16* __restrict__ owt,
    const float* __restrict__ ob, const float* __restrict__ x,
    float* __restrict__ y) {
  __shared__ u16 As[2][128 * 64];
  __shared__ u16 Bs[2][128 * 64];
  int tid = threadIdx.x, lane = tid & 63, wave = tid >> 6;
  int wy = wave >> 1, wx = wave & 1;
  int m0 = blockIdx.x * 128, n0 = blockIdx.y * 128;
  f32x4 acc[4][4];
#pragma unroll
  for (int i = 0; i < 4; ++i)
#pragma unroll
    for (int j = 0; j < 4; ++j) acc[i][j] = (f32x4)(0.f);

  const u16* agbase = comb + (size_t)m0 * DIM;
  const u16* bgbase = owt + (size_t)n0 * DIM;
  stage_tile(agbase, As[0], wave, lane);
  stage_tile(bgbase, Bs[0], wave, lane);
  __syncthreads();
#pragma unroll 1
  for (int it = 0; it < 8; ++it) {
    int cur = it & 1;
    int nxt = it + 1;
    if (nxt < 8) {
      stage_tile(agbase + nxt * 64, As[cur ^ 1], wave, lane);
      stage_tile(bgbase + nxt * 64, Bs[cur ^ 1], wave, lane);
    }
    gemm_step(As[cur], Bs[cur], lane, wy, wx, acc);
    __syncthreads();
  }
#pragma unroll
  for (int i = 0; i < 4; ++i) {
    int tb = m0 + wy * 64 + i * 16 + ((lane >> 4) << 2);
#pragma unroll
    for (int j = 0; j < 4; ++j) {
      int h = n0 + wx * 64 + j * 16 + (lane & 15);
      float bias = ob[h];
#pragma unroll
      for (int rr = 0; rr < 4; ++rr) {
        size_t idx = (size_t)(tb + rr) * DIM + h;
        y[idx] = x[idx] + acc[i][j][rr] + bias;
      }
    }
  }
}

// ---------------- K4: in-place RMSNorm on d_out ----------------
__global__ void rmsnorm_kernel(float* __restrict__ y, const float* __restrict__ nw) {
  int lane = threadIdx.x & 63, wave = threadIdx.x >> 6;
  size_t t = (size_t)blockIdx.x * 4 + wave;
  float* yr = y + t * DIM + lane * 8;
  f32x4 a = *(f32x4*)yr;
  f32x4 b = *(f32x4*)(yr + 4);
  float s = a[0]*a[0]+a[1]*a[1]+a[2]*a[2]+a[3]*a[3]
          + b[0]*b[0]+b[1]*b[1]+b[2]*b[2]+b[3]*b[3];
#pragma unroll
  for (int off = 32; off; off >>= 1) s += __shfl_xor(s, off);
  float inv = 1.0f / sqrtf(s * (1.0f / 512.0f) + 1e-6f);
  const float* nwp = nw + lane * 8;
  f32x4 w0 = *(const f32x4*)nwp;
  f32x4 w1 = *(const f32x4*)(nwp + 4);
#pragma unroll
  for (int q = 0; q < 4; ++q) { a[q] = a[q] * inv * w0[q]; b[q] = b[q] * inv * w1[q]; }
  *(f32x4*)yr = a;
  *(f32x4*)(yr + 4) = b;
}

extern "C" void kernel_launch(void* const* d_in, const int* in_sizes, int n_in,
                              void* d_out, int out_size, void* d_ws, size_t ws_size,
                              hipStream_t stream) {
  const float* x  = (const float*)d_in[0];
  const float* rw = (const float*)d_in[1];
  const float* rb = (const float*)d_in[2];
  const float* ew = (const float*)d_in[3];
  const float* eb = (const float*)d_in[4];
  const float* ow = (const float*)d_in[5];
  const float* ob = (const float*)d_in[6];
  const float* nw = (const float*)d_in[7];
  float* out = (float*)d_out;

  char* ws = (char*)d_ws;
  u16*  xb     = (u16*)(ws);                    // 64 MiB  x as bf16
  u16*  combb  = (u16*)(ws + 67108864);         // 64 MiB  combined expert out (bf16)
  u16*  ewt    = (u16*)(ws + 134217728);        // 2 MiB   expert_w^T bf16
  u16*  owt    = (u16*)(ws + 136314880);        // 0.5 MiB out_w^T bf16
  float* wmaskT = (float*)(ws + 136839168);     // 1 MiB   [E][T] routing weights

  wconv<<<dim3(256, 4), 256, 0, stream>>>(ew, ewt);
  wconv<<<dim3(256, 1), 256, 0, stream>>>(ow, owt);
  router_kernel<<<NTOK / 4, 256, 0, stream>>>(x, rw, rb, xb, wmaskT);
  expert_gemm<<<dim3(NTOK / 128, DIM / 128), 256, 0, stream>>>(xb, ewt, eb, wmaskT, combb);
  out_gemm<<<dim3(NTOK / 128, DIM / 128), 256, 0, stream>>>(combb, owt, ob, x, out);
  rmsnorm_kernel<<<NTOK / 4, 256, 0, stream>>>(out, nw);
}

// Round 2
// 470.171 us; speedup vs baseline: 1.0424x; 1.0424x over previous
//
#include <hip/hip_runtime.h>
#include <hip/hip_bf16.h>
#include <stdint.h>

#define NTOK 65536
#define DIM 512
#define NEXP 4
#define REG 14336  // per-pair-group slot region (expected ~10923, 36-sigma margin)

using u16 = unsigned short;
using u32 = unsigned int;
typedef __attribute__((ext_vector_type(4))) float f32x4;
typedef __attribute__((ext_vector_type(8))) short bf16x8;
typedef __attribute__((ext_vector_type(8))) u16 u16x8;

__device__ __forceinline__ u16 f2bf(float f) {
  u32 u = __builtin_bit_cast(u32, f);
  u32 r = (u + 0x7FFFu + ((u >> 16) & 1u)) >> 16;
  return (u16)r;
}

#define GLOAD_LDS16(gp, lp)                                                    \
  __builtin_amdgcn_global_load_lds(                                            \
      (const __attribute__((address_space(1))) void*)(gp),                     \
      (__attribute__((address_space(3))) void*)(lp), 16, 0, 0)

// ---------------- K0: weight transpose + fp32->bf16 ----------------
// dst[mat][h][d] = bf16(src[mat][d][h])   (N-major so MFMA B-frags are contiguous)
__global__ void wconv(const float* __restrict__ src, u16* __restrict__ dst) {
  __shared__ float tile[32][33];
  int mat = blockIdx.y;
  int tx = blockIdx.x & 15, ty = blockIdx.x >> 4;
  const float* s = src + (size_t)mat * DIM * DIM;
  u16* d = dst + (size_t)mat * DIM * DIM;
  int lx = threadIdx.x & 31, ly0 = threadIdx.x >> 5;
#pragma unroll
  for (int i = 0; i < 4; ++i) {
    int ly = ly0 + i * 8;
    tile[ly][lx] = s[(size_t)(ty * 32 + ly) * DIM + tx * 32 + lx];
  }
  __syncthreads();
#pragma unroll
  for (int i = 0; i < 4; ++i) {
    int ly = ly0 + i * 8;
    d[(size_t)(tx * 32 + ly) * DIM + ty * 32 + lx] = f2bf(tile[lx][ly]);
  }
}

// ---------------- K1: router (fp32) + x -> bf16 ----------------
// one wave per token; writes pair id pp[t] (0..5) and ordered weights wab[t]
__global__ void router_kernel(const float* __restrict__ x, const float* __restrict__ rw,
                              const float* __restrict__ rb, u16* __restrict__ xb,
                              int* __restrict__ pp, float2* __restrict__ wab) {
  int lane = threadIdx.x & 63, wave = threadIdx.x >> 6;
  size_t t = (size_t)blockIdx.x * 4 + wave;
  const float* xr = x + t * DIM + lane * 8;
  f32x4 v0 = *(const f32x4*)xr;
  f32x4 v1 = *(const f32x4*)(xr + 4);
  float l0 = 0.f, l1 = 0.f, l2 = 0.f, l3 = 0.f;
  const float* rwp = rw + (size_t)lane * 32;  // 8 rows x 4 experts
#pragma unroll
  for (int j = 0; j < 8; ++j) {
    float xv = (j < 4) ? v0[j] : v1[j - 4];
    f32x4 r = *(const f32x4*)(rwp + j * 4);
    l0 += xv * r[0]; l1 += xv * r[1]; l2 += xv * r[2]; l3 += xv * r[3];
  }
#pragma unroll
  for (int off = 32; off; off >>= 1) {
    l0 += __shfl_xor(l0, off); l1 += __shfl_xor(l1, off);
    l2 += __shfl_xor(l2, off); l3 += __shfl_xor(l3, off);
  }
  float lv[4] = {l0 + rb[0], l1 + rb[1], l2 + rb[2], l3 + rb[3]};
  int i0 = 0; float b0 = lv[0];
#pragma unroll
  for (int e = 1; e < 4; ++e) if (lv[e] > b0) { b0 = lv[e]; i0 = e; }
  int i1 = (i0 == 0) ? 1 : 0; float b1 = lv[i1];
#pragma unroll
  for (int e = 0; e < 4; ++e) if (e != i0 && lv[e] > b1) { b1 = lv[e]; i1 = e; }
  float ex = __expf(b1 - b0);
  float w0 = 1.0f / (1.0f + ex);
  float w1 = ex * w0;
  if (lane == 0) {
    int a = (i0 < i1) ? i0 : i1;
    int b = (i0 < i1) ? i1 : i0;
    // unordered-pair index: (0,1)=0 (0,2)=1 (0,3)=2 (1,2)=3 (1,3)=4 (2,3)=5
    const int ptab[16] = {-1, 0, 1, 2, -1, -1, 3, 4, -1, -1, -1, 5, -1, -1, -1, -1};
    pp[t] = ptab[a * 4 + b];
    float wa = (a == i0) ? w0 : w1;
    float wb = (a == i0) ? w1 : w0;
    wab[t] = make_float2(wa, wb);
  }
  u16x8 o;
#pragma unroll
  for (int j = 0; j < 4; ++j) { o[j] = f2bf(v0[j]); o[4 + j] = f2bf(v1[j]); }
  *(u16x8*)(xb + t * DIM + lane * 8) = o;
}

// ---------------- K2: wave-aggregated group assignment + scatter ----------------
__global__ void assignscatter(const int* __restrict__ pp, const float2* __restrict__ wab,
                              int* __restrict__ cnt, int* __restrict__ list,
                              float2* __restrict__ wpair) {
  int t = blockIdx.x * 256 + threadIdx.x;
  int lane = threadIdx.x & 63;
  int p = pp[t];
  float2 w = wab[t];
  int pos = 0;
#pragma unroll
  for (int q = 0; q < 6; ++q) {
    unsigned long long m = __ballot(p == q);
    if (p == q) {
      int rank = __popcll(m & ((1ull << lane) - 1ull));
      int leader = __ffsll((long long)m) - 1;
      int base = 0;
      if (lane == leader) base = atomicAdd(&cnt[q], (int)__popcll(m));
      base = __shfl(base, leader);
      pos = base + rank;
    }
  }
  int slot = p * REG + pos;
  if (pos < REG) {  // statistically impossible overflow guard
    list[slot] = t;
    wpair[slot] = w;
  }
}

// ---------------- shared GEMM pieces ----------------
// one BK=64 step: 16 ds_read_b128 + 32 MFMA per wave (64x64 wave tile)
__device__ __forceinline__ void gemm_step(const u16* As, const u16* Bs, int lane,
                                          int wy, int wx, f32x4 acc[4][4]) {
  int r = lane & 15, kof = (lane >> 4) * 8;
#pragma unroll
  for (int kc = 0; kc < 2; ++kc) {
    bf16x8 a[4], b[4];
#pragma unroll
    for (int i = 0; i < 4; ++i)
      a[i] = *(const bf16x8*)(As + (wy * 64 + i * 16 + r) * 64 + kc * 32 + kof);
#pragma unroll
    for (int i = 0; i < 4; ++i)
      b[i] = *(const bf16x8*)(Bs + (wx * 64 + i * 16 + r) * 64 + kc * 32 + kof);
#pragma unroll
    for (int i = 0; i < 4; ++i)
#pragma unroll
      for (int j = 0; j < 4; ++j)
        acc[i][j] = __builtin_amdgcn_mfma_f32_16x16x32_bf16(a[i], b[j], acc[i][j], 0, 0, 0);
  }
}

// ---------------- K3: sparse (pair-grouped) expert GEMM + SiLU + combine ----------------
__global__ __launch_bounds__(256, 2) void expert_gemm(
    const u16* __restrict__ xb, const u16* __restrict__ ewt,
    const float* __restrict__ ebias, const int* __restrict__ cnt,
    const int* __restrict__ list, const float2* __restrict__ wpair,
    u16* __restrict__ comb) {
  __shared__ u16 As[2][128 * 64];
  __shared__ u16 Bs[2][128 * 64];
  int tid = threadIdx.x, lane = tid & 63, wave = tid >> 6;
  int wy = wave >> 1, wx = wave & 1;
  int p = blockIdx.x / (REG / 128);
  int m0 = blockIdx.x * 128;       // global slot base
  int ml = m0 - p * REG;           // local offset within group
  if (ml >= cnt[p]) return;        // block entirely padding
  int n0 = blockIdx.y * 128;
  const int ea2[6] = {0, 0, 0, 1, 1, 2};
  const int eb2[6] = {1, 2, 3, 2, 3, 3};
  int eA = ea2[p], eB = eb2[p];

  int rl = lane >> 3, kb = (lane & 7) * 8;
  int sid[4];  // gathered token ids for this thread's stage rows (fixed over K)
#pragma unroll
  for (int j = 0; j < 4; ++j) {
    int idv = list[m0 + wave * 32 + j * 8 + rl];
    sid[j] = idv < 0 ? 0 : idv;  // pad rows load token 0 (finite; masked at write)
  }

  f32x4 acc[4][4], comba[4][4];
#pragma unroll
  for (int i = 0; i < 4; ++i)
#pragma unroll
    for (int j = 0; j < 4; ++j) { acc[i][j] = (f32x4)(0.f); comba[i][j] = (f32x4)(0.f); }

  // stage helpers: LDS dest linear (wave-uniform base); global src per-lane (gather)
#define STAGE_A(buf, ks)                                                       \
  _Pragma("unroll") for (int j = 0; j < 4; ++j) {                              \
    int row = wave * 32 + j * 8;                                               \
    GLOAD_LDS16(xb + (size_t)sid[j] * DIM + (ks) * 64 + kb, (buf) + row * 64); \
  }
#define STAGE_B(buf, e, ks)                                                    \
  _Pragma("unroll") for (int j = 0; j < 4; ++j) {                              \
    int row = wave * 32 + j * 8;                                               \
    GLOAD_LDS16(ewt + (size_t)(e) * DIM * DIM + (size_t)(n0 + row + rl) * DIM  \
                    + (ks) * 64 + kb,                                          \
                (buf) + row * 64);                                             \
  }

  STAGE_A(As[0], 0);
  STAGE_B(Bs[0], eA, 0);
  __syncthreads();

#pragma unroll 1
  for (int it = 0; it < 16; ++it) {
    int cur = it & 1;
    int nxt = it + 1;
    if (nxt < 16) {  // issue next-tile loads BEFORE compute (2-phase minimum)
      int e = (nxt >> 3) ? eB : eA;
      int ks = nxt & 7;
      STAGE_A(As[cur ^ 1], ks);
      STAGE_B(Bs[cur ^ 1], e, ks);
    }
    gemm_step(As[cur], Bs[cur], lane, wy, wx, acc);
    if ((it & 7) == 7) {  // per-expert epilogue: bias + SiLU + routed weight
      int e = (it >> 3) ? eB : eA;
      bool first = (it >> 3) == 0;
#pragma unroll
      for (int i = 0; i < 4; ++i) {
        int lrb = wy * 64 + i * 16 + ((lane >> 4) << 2);
        float wv[4];
#pragma unroll
        for (int rr = 0; rr < 4; ++rr) {
          float2 wp = wpair[m0 + lrb + rr];
          wv[rr] = first ? wp.x : wp.y;
        }
#pragma unroll
        for (int j = 0; j < 4; ++j) {
          int h = n0 + wx * 64 + j * 16 + (lane & 15);
          float bias = ebias[e * DIM + h];
#pragma unroll
          for (int rr = 0; rr < 4; ++rr) {
            float z = acc[i][j][rr] + bias;
            float sg = 1.0f / (1.0f + __expf(-z));
            comba[i][j][rr] += wv[rr] * (z * sg);
            acc[i][j][rr] = 0.0f;
          }
        }
      }
    }
    __syncthreads();
  }
  // scatter C-write by token id; pad rows (id<0) masked
#pragma unroll
  for (int i = 0; i < 4; ++i) {
    int lrb = wy * 64 + i * 16 + ((lane >> 4) << 2);
    int idw[4];
#pragma unroll
    for (int rr = 0; rr < 4; ++rr) idw[rr] = list[m0 + lrb + rr];
#pragma unroll
    for (int j = 0; j < 4; ++j) {
      int h = n0 + wx * 64 + j * 16 + (lane & 15);
#pragma unroll
      for (int rr = 0; rr < 4; ++rr)
        if (idw[rr] >= 0) comb[(size_t)idw[rr] * DIM + h] = f2bf(comba[i][j][rr]);
    }
  }
#undef STAGE_A
#undef STAGE_B
}

// ---------------- K4: out-proj GEMM + bias + fp32 residual -> y (in d_out) ----------------
__global__ __launch_bounds__(256, 2) void out_gemm(
    const u16* __restrict__ comb, const u16* __restrict__ owt,
    const float* __restrict__ ob, const float* __restrict__ x,
    float* __restrict__ y) {
  __shared__ u16 As[2][128 * 64];
  __shared__ u16 Bs[2][128 * 64];
  int tid = threadIdx.x, lane = tid & 63, wave = tid >> 6;
  int wy = wave >> 1, wx = wave & 1;
  int m0 = blockIdx.x * 128, n0 = blockIdx.y * 128;
  int rl = lane >> 3, kb = (lane & 7) * 8;
  f32x4 acc[4][4];
#pragma unroll
  for (int i = 0; i < 4; ++i)
#pragma unroll
    for (int j = 0; j < 4; ++j) acc[i][j] = (f32x4)(0.f);

#define STAGE_G(buf, g, ks)                                                    \
  _Pragma("unroll") for (int j = 0; j < 4; ++j) {                              \
    int row = wave * 32 + j * 8;                                               \
    GLOAD_LDS16((g) + (size_t)(row + rl) * DIM + (ks) * 64 + kb, (buf) + row * 64); \
  }

  const u16* agbase = comb + (size_t)m0 * DIM;
  const u16* bgbase = owt + (size_t)n0 * DIM;
  STAGE_G(As[0], agbase, 0);
  STAGE_G(Bs[0], bgbase, 0);
  __syncthreads();
#pragma unroll 1
  for (int it = 0; it < 8; ++it) {
    int cur = it & 1;
    int nxt = it + 1;
    if (nxt < 8) {
      STAGE_G(As[cur ^ 1], agbase, nxt);
      STAGE_G(Bs[cur ^ 1], bgbase, nxt);
    }
    gemm_step(As[cur], Bs[cur], lane, wy, wx, acc);
    __syncthreads();
  }
#pragma unroll
  for (int i = 0; i < 4; ++i) {
    int tb = m0 + wy * 64 + i * 16 + ((lane >> 4) << 2);
#pragma unroll
    for (int j = 0; j < 4; ++j) {
      int h = n0 + wx * 64 + j * 16 + (lane & 15);
      float bias = ob[h];
#pragma unroll
      for (int rr = 0; rr < 4; ++rr) {
        size_t idx = (size_t)(tb + rr) * DIM + h;
        y[idx] = x[idx] + acc[i][j][rr] + bias;
      }
    }
  }
#undef STAGE_G
}

// ---------------- K5: in-place RMSNorm on d_out ----------------
__global__ void rmsnorm_kernel(float* __restrict__ y, const float* __restrict__ nw) {
  int lane = threadIdx.x & 63, wave = threadIdx.x >> 6;
  size_t t = (size_t)blockIdx.x * 4 + wave;
  float* yr = y + t * DIM + lane * 8;
  f32x4 a = *(f32x4*)yr;
  f32x4 b = *(f32x4*)(yr + 4);
  float s = a[0]*a[0]+a[1]*a[1]+a[2]*a[2]+a[3]*a[3]
          + b[0]*b[0]+b[1]*b[1]+b[2]*b[2]+b[3]*b[3];
#pragma unroll
  for (int off = 32; off; off >>= 1) s += __shfl_xor(s, off);
  float inv = 1.0f / sqrtf(s * (1.0f / 512.0f) + 1e-6f);
  const float* nwp = nw + lane * 8;
  f32x4 w0 = *(const f32x4*)nwp;
  f32x4 w1 = *(const f32x4*)(nwp + 4);
#pragma unroll
  for (int q = 0; q < 4; ++q) { a[q] = a[q] * inv * w0[q]; b[q] = b[q] * inv * w1[q]; }
  *(f32x4*)yr = a;
  *(f32x4*)(yr + 4) = b;
}

extern "C" void kernel_launch(void* const* d_in, const int* in_sizes, int n_in,
                              void* d_out, int out_size, void* d_ws, size_t ws_size,
                              hipStream_t stream) {
  const float* x  = (const float*)d_in[0];
  const float* rw = (const float*)d_in[1];
  const float* rb = (const float*)d_in[2];
  const float* ew = (const float*)d_in[3];
  const float* eb = (const float*)d_in[4];
  const float* ow = (const float*)d_in[5];
  const float* ob = (const float*)d_in[6];
  const float* nw = (const float*)d_in[7];
  float* out = (float*)d_out;

  char* ws = (char*)d_ws;
  u16*   xb    = (u16*)(ws);                      // 64 MiB  x as bf16
  u16*   combb = (u16*)(ws + 67108864);           // 64 MiB  combined expert out (bf16)
  // pp/wab live inside combb region (dead before expert_gemm writes combb)
  int*   pp    = (int*)(ws + 67108864);           // 256 KiB per-token pair id
  float2* wab  = (float2*)(ws + 67108864 + 262144); // 512 KiB per-token ordered weights
  u16*   ewt   = (u16*)(ws + 134217728);          // 2 MiB   expert_w^T bf16
  u16*   owt   = (u16*)(ws + 136314880);          // 0.5 MiB out_w^T bf16
  int*   list  = (int*)(ws + 136839168);          // 336 KiB [6][REG] token ids
  float2* wpair = (float2*)(ws + 136839168 + 344064); // 672 KiB [6][REG] weights
  int*   cnt   = (int*)(ws + 136839168 + 344064 + 688128); // 24 B group counts

  hipMemsetAsync(cnt, 0, 24, stream);
  hipMemsetAsync(list, 0xFF, 6 * REG * 4, stream);  // -1 = pad slot
  wconv<<<dim3(256, 4), 256, 0, stream>>>(ew, ewt);
  wconv<<<dim3(256, 1), 256, 0, stream>>>(ow, owt);
  router_kernel<<<NTOK / 4, 256, 0, stream>>>(x, rw, rb, xb, pp, wab);
  assignscatter<<<NTOK / 256, 256, 0, stream>>>(pp, wab, cnt, list, wpair);
  expert_gemm<<<dim3(6 * REG / 128, DIM / 128), 256, 0, stream>>>(xb, ewt, eb, cnt, list, wpair, combb);
  out_gemm<<<dim3(NTOK / 128, DIM / 128), 256, 0, stream>>>(combb, owt, ob, x, out);
  rmsnorm_kernel<<<NTOK / 4, 256, 0, stream>>>(out, nw);
}

// Round 3
// 411.660 us; speedup vs baseline: 1.1905x; 1.1421x over previous
//
#include <hip/hip_runtime.h>
#include <hip/hip_bf16.h>
#include <stdint.h>

#define NTOK 65536
#define DIM 512
#define NEXP 4
#define REG 14336  // per-pair-group slot region (expected ~10923, 36-sigma margin)

using u16 = unsigned short;
using u32 = unsigned int;
typedef __attribute__((ext_vector_type(4))) float f32x4;
typedef __attribute__((ext_vector_type(8))) short bf16x8;
typedef __attribute__((ext_vector_type(8))) u16 u16x8;

__device__ __forceinline__ u16 f2bf(float f) {
  u32 u = __builtin_bit_cast(u32, f);
  u32 r = (u + 0x7FFFu + ((u >> 16) & 1u)) >> 16;
  return (u16)r;
}

#define GLOAD_LDS16(gp, lp)                                                    \
  __builtin_amdgcn_global_load_lds(                                            \
      (const __attribute__((address_space(1))) void*)(gp),                     \
      (__attribute__((address_space(3))) void*)(lp), 16, 0, 0)

// ---------------- K0: weight transpose + fp32->bf16 ----------------
__global__ void wconv(const float* __restrict__ src, u16* __restrict__ dst) {
  __shared__ float tile[32][33];
  int mat = blockIdx.y;
  int tx = blockIdx.x & 15, ty = blockIdx.x >> 4;
  const float* s = src + (size_t)mat * DIM * DIM;
  u16* d = dst + (size_t)mat * DIM * DIM;
  int lx = threadIdx.x & 31, ly0 = threadIdx.x >> 5;
#pragma unroll
  for (int i = 0; i < 4; ++i) {
    int ly = ly0 + i * 8;
    tile[ly][lx] = s[(size_t)(ty * 32 + ly) * DIM + tx * 32 + lx];
  }
  __syncthreads();
#pragma unroll
  for (int i = 0; i < 4; ++i) {
    int ly = ly0 + i * 8;
    d[(size_t)(tx * 32 + ly) * DIM + ty * 32 + lx] = f2bf(tile[lx][ly]);
  }
}

// ---------------- K1: router (fp32) + x -> bf16 ----------------
__global__ void router_kernel(const float* __restrict__ x, const float* __restrict__ rw,
                              const float* __restrict__ rb, u16* __restrict__ xb,
                              int* __restrict__ pp, float2* __restrict__ wab) {
  int lane = threadIdx.x & 63, wave = threadIdx.x >> 6;
  size_t t = (size_t)blockIdx.x * 4 + wave;
  const float* xr = x + t * DIM + lane * 8;
  f32x4 v0 = *(const f32x4*)xr;
  f32x4 v1 = *(const f32x4*)(xr + 4);
  float l0 = 0.f, l1 = 0.f, l2 = 0.f, l3 = 0.f;
  const float* rwp = rw + (size_t)lane * 32;
#pragma unroll
  for (int j = 0; j < 8; ++j) {
    float xv = (j < 4) ? v0[j] : v1[j - 4];
    f32x4 r = *(const f32x4*)(rwp + j * 4);
    l0 += xv * r[0]; l1 += xv * r[1]; l2 += xv * r[2]; l3 += xv * r[3];
  }
#pragma unroll
  for (int off = 32; off; off >>= 1) {
    l0 += __shfl_xor(l0, off); l1 += __shfl_xor(l1, off);
    l2 += __shfl_xor(l2, off); l3 += __shfl_xor(l3, off);
  }
  float lv[4] = {l0 + rb[0], l1 + rb[1], l2 + rb[2], l3 + rb[3]};
  int i0 = 0; float b0 = lv[0];
#pragma unroll
  for (int e = 1; e < 4; ++e) if (lv[e] > b0) { b0 = lv[e]; i0 = e; }
  int i1 = (i0 == 0) ? 1 : 0; float b1 = lv[i1];
#pragma unroll
  for (int e = 0; e < 4; ++e) if (e != i0 && lv[e] > b1) { b1 = lv[e]; i1 = e; }
  float ex = __expf(b1 - b0);
  float w0 = 1.0f / (1.0f + ex);
  float w1 = ex * w0;
  if (lane == 0) {
    int a = (i0 < i1) ? i0 : i1;
    int b = (i0 < i1) ? i1 : i0;
    const int ptab[16] = {-1, 0, 1, 2, -1, -1, 3, 4, -1, -1, -1, 5, -1, -1, -1, -1};
    pp[t] = ptab[a * 4 + b];
    float wa = (a == i0) ? w0 : w1;
    float wb = (a == i0) ? w1 : w0;
    wab[t] = make_float2(wa, wb);
  }
  u16x8 o;
#pragma unroll
  for (int j = 0; j < 4; ++j) { o[j] = f2bf(v0[j]); o[4 + j] = f2bf(v1[j]); }
  *(u16x8*)(xb + t * DIM + lane * 8) = o;
}

// ---------------- K2: wave-aggregated group assignment + scatter ----------------
__global__ void assignscatter(const int* __restrict__ pp, const float2* __restrict__ wab,
                              int* __restrict__ cnt, int* __restrict__ list,
                              float2* __restrict__ wpair) {
  int t = blockIdx.x * 256 + threadIdx.x;
  int lane = threadIdx.x & 63;
  int p = pp[t];
  float2 w = wab[t];
  int pos = 0;
#pragma unroll
  for (int q = 0; q < 6; ++q) {
    unsigned long long m = __ballot(p == q);
    if (p == q) {
      int rank = __popcll(m & ((1ull << lane) - 1ull));
      int leader = __ffsll((long long)m) - 1;
      int base = 0;
      if (lane == leader) base = atomicAdd(&cnt[q], (int)__popcll(m));
      base = __shfl(base, leader);
      pos = base + rank;
    }
  }
  int slot = p * REG + pos;
  if (pos < REG) {
    list[slot] = t;
    wpair[slot] = w;
  }
}

// ---------------- shared GEMM piece ----------------
__device__ __forceinline__ void gemm_step(const u16* As, const u16* Bs, int lane,
                                          int wy, int wx, f32x4 acc[4][4]) {
  int r = lane & 15, kof = (lane >> 4) * 8;
#pragma unroll
  for (int kc = 0; kc < 2; ++kc) {
    bf16x8 a[4], b[4];
#pragma unroll
    for (int i = 0; i < 4; ++i)
      a[i] = *(const bf16x8*)(As + (wy * 64 + i * 16 + r) * 64 + kc * 32 + kof);
#pragma unroll
    for (int i = 0; i < 4; ++i)
      b[i] = *(const bf16x8*)(Bs + (wx * 64 + i * 16 + r) * 64 + kc * 32 + kof);
#pragma unroll
    for (int i = 0; i < 4; ++i)
#pragma unroll
      for (int j = 0; j < 4; ++j)
        acc[i][j] = __builtin_amdgcn_mfma_f32_16x16x32_bf16(a[i], b[j], acc[i][j], 0, 0, 0);
  }
}

// ---------------- K3: sparse expert GEMM + SiLU + combine (XCD-swizzled grid) ----------------
__global__ __launch_bounds__(256, 2) void expert_gemm(
    const u16* __restrict__ xb, const u16* __restrict__ ewt,
    const float* __restrict__ ebias, const int* __restrict__ cnt,
    const int* __restrict__ list, const float2* __restrict__ wpair,
    u16* __restrict__ comb) {
  __shared__ u16 As[2][128 * 64];
  __shared__ u16 Bs[2][128 * 64];
  int tid = threadIdx.x, lane = tid & 63, wave = tid >> 6;
  int wy = wave >> 1, wx = wave & 1;
  // XCD swizzle: 4 n-blocks of one M-panel get flat ids == same (mod 8)
  // -> same XCD, adjacent dispatch -> A-panel L2-shared.
  int b = blockIdx.x;
  int chunk = b >> 5, within = b & 31;
  int panel = chunk * 8 + (within & 7);  // 0..671 (672 % 8 == 0: bijective)
  int nblk = within >> 3;                // 0..3
  int p = panel / (REG / 128);
  int m0 = panel * 128;
  int ml = m0 - p * REG;
  if (ml >= cnt[p]) return;
  int n0 = nblk * 128;
  const int ea2[6] = {0, 0, 0, 1, 1, 2};
  const int eb2[6] = {1, 2, 3, 2, 3, 3};
  int eA = ea2[p], eB = eb2[p];

  int rl = lane >> 3, kb = (lane & 7) * 8;
  int sid[4];
#pragma unroll
  for (int j = 0; j < 4; ++j) {
    int idv = list[m0 + wave * 32 + j * 8 + rl];
    sid[j] = idv < 0 ? 0 : idv;
  }

  f32x4 acc[4][4], comba[4][4];
#pragma unroll
  for (int i = 0; i < 4; ++i)
#pragma unroll
    for (int j = 0; j < 4; ++j) { acc[i][j] = (f32x4)(0.f); comba[i][j] = (f32x4)(0.f); }

#define STAGE_A(buf, ks)                                                       \
  _Pragma("unroll") for (int j = 0; j < 4; ++j) {                              \
    int row = wave * 32 + j * 8;                                               \
    GLOAD_LDS16(xb + (size_t)sid[j] * DIM + (ks) * 64 + kb, (buf) + row * 64); \
  }
#define STAGE_B(buf, e, ks)                                                    \
  _Pragma("unroll") for (int j = 0; j < 4; ++j) {                              \
    int row = wave * 32 + j * 8;                                               \
    GLOAD_LDS16(ewt + (size_t)(e) * DIM * DIM + (size_t)(n0 + row + rl) * DIM  \
                    + (ks) * 64 + kb,                                          \
                (buf) + row * 64);                                             \
  }

  STAGE_A(As[0], 0);
  STAGE_B(Bs[0], eA, 0);
  __syncthreads();

#pragma unroll 1
  for (int it = 0; it < 16; ++it) {
    int cur = it & 1;
    int nxt = it + 1;
    if (nxt < 16) {
      int e = (nxt >> 3) ? eB : eA;
      int ks = nxt & 7;
      STAGE_A(As[cur ^ 1], ks);
      STAGE_B(Bs[cur ^ 1], e, ks);
    }
    gemm_step(As[cur], Bs[cur], lane, wy, wx, acc);
    if ((it & 7) == 7) {
      int e = (it >> 3) ? eB : eA;
      bool first = (it >> 3) == 0;
#pragma unroll
      for (int i = 0; i < 4; ++i) {
        int lrb = wy * 64 + i * 16 + ((lane >> 4) << 2);
        float wv[4];
#pragma unroll
        for (int rr = 0; rr < 4; ++rr) {
          float2 wp = wpair[m0 + lrb + rr];
          wv[rr] = first ? wp.x : wp.y;
        }
#pragma unroll
        for (int j = 0; j < 4; ++j) {
          int h = n0 + wx * 64 + j * 16 + (lane & 15);
          float bias = ebias[e * DIM + h];
#pragma unroll
          for (int rr = 0; rr < 4; ++rr) {
            float z = acc[i][j][rr] + bias;
            float sg = 1.0f / (1.0f + __expf(-z));
            comba[i][j][rr] += wv[rr] * (z * sg);
            acc[i][j][rr] = 0.0f;
          }
        }
      }
    }
    __syncthreads();
  }
#pragma unroll
  for (int i = 0; i < 4; ++i) {
    int lrb = wy * 64 + i * 16 + ((lane >> 4) << 2);
    int idw[4];
#pragma unroll
    for (int rr = 0; rr < 4; ++rr) idw[rr] = list[m0 + lrb + rr];
#pragma unroll
    for (int j = 0; j < 4; ++j) {
      int h = n0 + wx * 64 + j * 16 + (lane & 15);
#pragma unroll
      for (int rr = 0; rr < 4; ++rr)
        if (idw[rr] >= 0) comb[(size_t)idw[rr] * DIM + h] = f2bf(comba[i][j][rr]);
    }
  }
#undef STAGE_A
#undef STAGE_B
}

// ---------------- K4: fused out-proj + bias + residual + RMSNorm ----------------
// BM=128 tokens/block, full N=512. 8 waves (2 wy x 4 wx), wave tile 64x128.
// A (comb) via LDS dbuf; B (out_w, L2-hot) read directly to register frags.
__global__ __launch_bounds__(512, 1) void outnorm(
    const u16* __restrict__ comb, const u16* __restrict__ owt,
    const float* __restrict__ ob, const float* __restrict__ x,
    const float* __restrict__ nw, float* __restrict__ out) {
  __shared__ u16 As[2][128 * 64];
  __shared__ float rowsum[128][4];
  int tid = threadIdx.x, lane = tid & 63, wave = tid >> 6;  // 8 waves
  int wy = wave >> 2, wx = wave & 3;
  int m0 = blockIdx.x * 128;
  int r = lane & 15, lg = lane >> 4;

  f32x4 acc[4][8];
#pragma unroll
  for (int i = 0; i < 4; ++i)
#pragma unroll
    for (int j = 0; j < 8; ++j) acc[i][j] = (f32x4)(0.f);

  int rl = lane >> 3, kb = (lane & 7) * 8;
  // wave w stages comb rows w*16 .. w*16+15 (2 instrs of 8 rows each)
#define STG(buf, ks)                                                           \
  _Pragma("unroll") for (int j = 0; j < 2; ++j) {                              \
    int row = wave * 16 + j * 8;                                               \
    GLOAD_LDS16(comb + (size_t)(m0 + row + rl) * DIM + (ks) * 64 + kb,         \
                (buf) + row * 64);                                             \
  }

  STG(As[0], 0);
  __syncthreads();
#pragma unroll 1
  for (int it = 0; it < 8; ++it) {
    int cur = it & 1;
    if (it < 7) STG(As[cur ^ 1], it + 1);
    const u16* Ab = As[cur];
#pragma unroll
    for (int kc = 0; kc < 2; ++kc) {
      bf16x8 bfr[8];
#pragma unroll
      for (int j = 0; j < 8; ++j)
        bfr[j] = *(const bf16x8*)(owt + (size_t)(wx * 128 + j * 16 + r) * DIM +
                                  it * 64 + kc * 32 + lg * 8);
      bf16x8 afr[4];
#pragma unroll
      for (int i = 0; i < 4; ++i)
        afr[i] = *(const bf16x8*)(Ab + (wy * 64 + i * 16 + r) * 64 + kc * 32 + lg * 8);
#pragma unroll
      for (int i = 0; i < 4; ++i)
#pragma unroll
        for (int j = 0; j < 8; ++j)
          acc[i][j] = __builtin_amdgcn_mfma_f32_16x16x32_bf16(afr[i], bfr[j], acc[i][j], 0, 0, 0);
    }
    __syncthreads();
  }
#undef STG

  // epilogue: y = x + out + bias; rowsum of y^2; then RMSNorm write
  float part[4][4];
#pragma unroll
  for (int i = 0; i < 4; ++i)
#pragma unroll
    for (int rr = 0; rr < 4; ++rr) part[i][rr] = 0.f;
#pragma unroll
  for (int i = 0; i < 4; ++i) {
#pragma unroll
    for (int j = 0; j < 8; ++j) {
      int h = wx * 128 + j * 16 + r;
      float bias = ob[h];
#pragma unroll
      for (int rr = 0; rr < 4; ++rr) {
        int lr = wy * 64 + i * 16 + lg * 4 + rr;
        float yv = x[(size_t)(m0 + lr) * DIM + h] + acc[i][j][rr] + bias;
        acc[i][j][rr] = yv;
        part[i][rr] += yv * yv;
      }
    }
  }
  // reduce across the 16 lanes sharing the same rows (lane&15)
#pragma unroll
  for (int off = 1; off < 16; off <<= 1)
#pragma unroll
    for (int i = 0; i < 4; ++i)
#pragma unroll
      for (int rr = 0; rr < 4; ++rr) part[i][rr] += __shfl_xor(part[i][rr], off);
  if (r == 0) {
#pragma unroll
    for (int i = 0; i < 4; ++i)
#pragma unroll
      for (int rr = 0; rr < 4; ++rr)
        rowsum[wy * 64 + i * 16 + lg * 4 + rr][wx] = part[i][rr];
  }
  __syncthreads();
  float inv[4][4];
#pragma unroll
  for (int i = 0; i < 4; ++i)
#pragma unroll
    for (int rr = 0; rr < 4; ++rr) {
      int lr = wy * 64 + i * 16 + lg * 4 + rr;
      float s = rowsum[lr][0] + rowsum[lr][1] + rowsum[lr][2] + rowsum[lr][3];
      inv[i][rr] = 1.0f / sqrtf(s * (1.0f / 512.0f) + 1e-6f);
    }
#pragma unroll
  for (int i = 0; i < 4; ++i) {
#pragma unroll
    for (int j = 0; j < 8; ++j) {
      int h = wx * 128 + j * 16 + r;
      float wv = nw[h];
#pragma unroll
      for (int rr = 0; rr < 4; ++rr) {
        int lr = wy * 64 + i * 16 + lg * 4 + rr;
        out[(size_t)(m0 + lr) * DIM + h] = acc[i][j][rr] * inv[i][rr] * wv;
      }
    }
  }
}

extern "C" void kernel_launch(void* const* d_in, const int* in_sizes, int n_in,
                              void* d_out, int out_size, void* d_ws, size_t ws_size,
                              hipStream_t stream) {
  const float* x  = (const float*)d_in[0];
  const float* rw = (const float*)d_in[1];
  const float* rb = (const float*)d_in[2];
  const float* ew = (const float*)d_in[3];
  const float* eb = (const float*)d_in[4];
  const float* ow = (const float*)d_in[5];
  const float* ob = (const float*)d_in[6];
  const float* nw = (const float*)d_in[7];
  float* out = (float*)d_out;

  char* ws = (char*)d_ws;
  u16*   xb    = (u16*)(ws);                        // 64 MiB  x as bf16
  u16*   combb = (u16*)(ws + 67108864);             // 64 MiB  combined expert out (bf16)
  int*   pp    = (int*)(ws + 67108864);             // aliases combb (dead before it's written)
  float2* wab  = (float2*)(ws + 67108864 + 262144);
  u16*   ewt   = (u16*)(ws + 134217728);            // 2 MiB   expert_w^T bf16
  u16*   owt   = (u16*)(ws + 136314880);            // 0.5 MiB out_w^T bf16
  int*   list  = (int*)(ws + 136839168);            // 336 KiB [6][REG] token ids
  float2* wpair = (float2*)(ws + 136839168 + 344064); // 672 KiB [6][REG] weights
  int*   cnt   = (int*)(ws + 136839168 + 344064 + 688128); // 24 B group counts

  hipMemsetAsync(cnt, 0, 24, stream);
  hipMemsetAsync(list, 0xFF, 6 * REG * 4, stream);
  wconv<<<dim3(256, 4), 256, 0, stream>>>(ew, ewt);
  wconv<<<dim3(256, 1), 256, 0, stream>>>(ow, owt);
  router_kernel<<<NTOK / 4, 256, 0, stream>>>(x, rw, rb, xb, pp, wab);
  assignscatter<<<NTOK / 256, 256, 0, stream>>>(pp, wab, cnt, list, wpair);
  expert_gemm<<<dim3(6 * REG / 128 * 4), 256, 0, stream>>>(xb, ewt, eb, cnt, list, wpair, combb);
  outnorm<<<dim3(NTOK / 128), 512, 0, stream>>>(combb, owt, ob, x, nw, out);
}

// Round 4
// 397.579 us; speedup vs baseline: 1.2327x; 1.0354x over previous
//
#include <hip/hip_runtime.h>
#include <hip/hip_bf16.h>
#include <stdint.h>

#define NTOK 65536
#define DIM 512
#define NEXP 4
#define REG 14336  // per-pair-group slot region (expected ~10923, 36-sigma margin)

using u16 = unsigned short;
using u32 = unsigned int;
typedef __attribute__((ext_vector_type(4))) float f32x4;
typedef __attribute__((ext_vector_type(8))) short bf16x8;
typedef __attribute__((ext_vector_type(8))) u16 u16x8;

__device__ __forceinline__ u16 f2bf(float f) {
  u32 u = __builtin_bit_cast(u32, f);
  u32 r = (u + 0x7FFFu + ((u >> 16) & 1u)) >> 16;
  return (u16)r;
}

#define GLOAD_LDS16(gp, lp)                                                    \
  __builtin_amdgcn_global_load_lds(                                            \
      (const __attribute__((address_space(1))) void*)(gp),                     \
      (__attribute__((address_space(3))) void*)(lp), 16, 0, 0)

#define FENCE asm volatile("" ::: "memory")
#define BARRIER { FENCE; __builtin_amdgcn_s_barrier(); FENCE; }
#define LGKM0 { asm volatile("s_waitcnt lgkmcnt(0)" ::: "memory"); __builtin_amdgcn_sched_barrier(0); }
#define VMCNT_(n) asm volatile("s_waitcnt vmcnt(" #n ")" ::: "memory")
#define VMCNT(n) VMCNT_(n)

// swizzled LDS read: logical (row, 16B-chunk) -> physical byte. Stage side uses
// inverse-permuted global SOURCE (chunk src = (l&7) ^ (l>>3)) with linear dest,
// so read chunk' = chunk ^ (row&7). Involution; rows 0..7 spread over 8 slots.
__device__ __forceinline__ const bf16x8* lds_frag(const u16* base, int row, int chunk) {
  return (const bf16x8*)((const char*)base + row * 128 + (((chunk) ^ (row & 7)) << 4));
}

// ---------------- K0: weight transpose + fp32->bf16 ----------------
__global__ void wconv(const float* __restrict__ src, u16* __restrict__ dst) {
  __shared__ float tile[32][33];
  int mat = blockIdx.y;
  int tx = blockIdx.x & 15, ty = blockIdx.x >> 4;
  const float* s = src + (size_t)mat * DIM * DIM;
  u16* d = dst + (size_t)mat * DIM * DIM;
  int lx = threadIdx.x & 31, ly0 = threadIdx.x >> 5;
#pragma unroll
  for (int i = 0; i < 4; ++i) {
    int ly = ly0 + i * 8;
    tile[ly][lx] = s[(size_t)(ty * 32 + ly) * DIM + tx * 32 + lx];
  }
  __syncthreads();
#pragma unroll
  for (int i = 0; i < 4; ++i) {
    int ly = ly0 + i * 8;
    d[(size_t)(tx * 32 + ly) * DIM + ty * 32 + lx] = f2bf(tile[lx][ly]);
  }
}

// ---------------- K1: router (fp32) + x -> bf16 ----------------
__global__ void router_kernel(const float* __restrict__ x, const float* __restrict__ rw,
                              const float* __restrict__ rb, u16* __restrict__ xb,
                              int* __restrict__ pp, float2* __restrict__ wab) {
  int lane = threadIdx.x & 63, wave = threadIdx.x >> 6;
  size_t t = (size_t)blockIdx.x * 4 + wave;
  const float* xr = x + t * DIM + lane * 8;
  f32x4 v0 = *(const f32x4*)xr;
  f32x4 v1 = *(const f32x4*)(xr + 4);
  float l0 = 0.f, l1 = 0.f, l2 = 0.f, l3 = 0.f;
  const float* rwp = rw + (size_t)lane * 32;
#pragma unroll
  for (int j = 0; j < 8; ++j) {
    float xv = (j < 4) ? v0[j] : v1[j - 4];
    f32x4 r = *(const f32x4*)(rwp + j * 4);
    l0 += xv * r[0]; l1 += xv * r[1]; l2 += xv * r[2]; l3 += xv * r[3];
  }
#pragma unroll
  for (int off = 32; off; off >>= 1) {
    l0 += __shfl_xor(l0, off); l1 += __shfl_xor(l1, off);
    l2 += __shfl_xor(l2, off); l3 += __shfl_xor(l3, off);
  }
  float lv[4] = {l0 + rb[0], l1 + rb[1], l2 + rb[2], l3 + rb[3]};
  int i0 = 0; float b0 = lv[0];
#pragma unroll
  for (int e = 1; e < 4; ++e) if (lv[e] > b0) { b0 = lv[e]; i0 = e; }
  int i1 = (i0 == 0) ? 1 : 0; float b1 = lv[i1];
#pragma unroll
  for (int e = 0; e < 4; ++e) if (e != i0 && lv[e] > b1) { b1 = lv[e]; i1 = e; }
  float ex = __expf(b1 - b0);
  float w0 = 1.0f / (1.0f + ex);
  float w1 = ex * w0;
  if (lane == 0) {
    int a = (i0 < i1) ? i0 : i1;
    int b = (i0 < i1) ? i1 : i0;
    const int ptab[16] = {-1, 0, 1, 2, -1, -1, 3, 4, -1, -1, -1, 5, -1, -1, -1, -1};
    pp[t] = ptab[a * 4 + b];
    float wa = (a == i0) ? w0 : w1;
    float wb = (a == i0) ? w1 : w0;
    wab[t] = make_float2(wa, wb);
  }
  u16x8 o;
#pragma unroll
  for (int j = 0; j < 4; ++j) { o[j] = f2bf(v0[j]); o[4 + j] = f2bf(v1[j]); }
  *(u16x8*)(xb + t * DIM + lane * 8) = o;
}

// ---------------- K2: wave-aggregated group assignment + scatter ----------------
__global__ void assignscatter(const int* __restrict__ pp, const float2* __restrict__ wab,
                              int* __restrict__ cnt, int* __restrict__ list,
                              float2* __restrict__ wpair) {
  int t = blockIdx.x * 256 + threadIdx.x;
  int lane = threadIdx.x & 63;
  int p = pp[t];
  float2 w = wab[t];
  int pos = 0;
#pragma unroll
  for (int q = 0; q < 6; ++q) {
    unsigned long long m = __ballot(p == q);
    if (p == q) {
      int rank = __popcll(m & ((1ull << lane) - 1ull));
      int leader = __ffsll((long long)m) - 1;
      int base = 0;
      if (lane == leader) base = atomicAdd(&cnt[q], (int)__popcll(m));
      base = __shfl(base, leader);
      pos = base + rank;
    }
  }
  int slot = p * REG + pos;
  if (pos < REG) {
    list[slot] = t;
    wpair[slot] = w;
  }
}

// ---------------- K3: sparse expert GEMM + SiLU + combine ----------------
// 128x128 tile, 4 waves, BK=64, 16 K-tiles (2 experts x 8). Pipelined:
// 2-deep LDS prefetch, counted vmcnt(8), swizzled LDS, setprio MFMA clusters.
__global__ __launch_bounds__(256, 2) void expert_gemm(
    const u16* __restrict__ xb, const u16* __restrict__ ewt,
    const float* __restrict__ ebias, const int* __restrict__ cnt,
    const int* __restrict__ list, const float2* __restrict__ wpair,
    u16* __restrict__ comb) {
  __shared__ u16 Asb[2][128 * 64];
  __shared__ u16 Bsb[2][128 * 64];
  int tid = threadIdx.x, lane = tid & 63, wave = tid >> 6;
  int wy = wave >> 1, wx = wave & 1;
  // XCD swizzle: 4 n-blocks of one M-panel -> same XCD, adjacent dispatch.
  int b = blockIdx.x;
  int chunk = b >> 5, within = b & 31;
  int panel = chunk * 8 + (within & 7);  // 0..671 (bijective: 672 % 8 == 0)
  int nblk = within >> 3;                // 0..3
  int p = panel / (REG / 128);
  int m0 = panel * 128;
  int ml = m0 - p * REG;
  if (ml >= cnt[p]) return;
  int n0 = nblk * 128;
  const int ea2[6] = {0, 0, 0, 1, 1, 2};
  const int eb2[6] = {1, 2, 3, 2, 3, 3};
  int eA = ea2[p], eB = eb2[p];

  int rl = lane >> 3;                 // 0..7 (staging row within 8-row group)
  int scb = ((lane & 7) ^ rl) * 8;    // pre-swizzled source column (u16 elems)
  int r16 = lane & 15, lg = lane >> 4;
  int sid[4];
#pragma unroll
  for (int j = 0; j < 4; ++j) {
    int idv = list[m0 + wave * 32 + j * 8 + rl];
    sid[j] = idv < 0 ? 0 : idv;
  }

  f32x4 acc[4][4], comba[4][4];
#pragma unroll
  for (int i = 0; i < 4; ++i)
#pragma unroll
    for (int j = 0; j < 4; ++j) { acc[i][j] = (f32x4)(0.f); comba[i][j] = (f32x4)(0.f); }

#define STAGE_A(buf, ks)                                                       \
  _Pragma("unroll") for (int j = 0; j < 4; ++j) {                              \
    GLOAD_LDS16(xb + (size_t)sid[j] * DIM + (ks) * 64 + scb,                   \
                (buf) + (wave * 32 + j * 8) * 64);                             \
  }
#define STAGE_B(buf, e, ks)                                                    \
  _Pragma("unroll") for (int j = 0; j < 4; ++j) {                              \
    GLOAD_LDS16(ewt + (size_t)(e) * DIM * DIM +                                \
                    (size_t)(n0 + wave * 32 + j * 8 + rl) * DIM + (ks) * 64 + scb, \
                (buf) + (wave * 32 + j * 8) * 64);                             \
  }

  // prologue: tiles 0 and 1 in flight; gate tile 0 (8 newest = tile 1 stay out)
  STAGE_A(Asb[0], 0); STAGE_B(Bsb[0], eA, 0);
  STAGE_A(Asb[1], 1); STAGE_B(Bsb[1], eA, 1);
  VMCNT(8);
  BARRIER;

#pragma unroll 1
  for (int t = 0; t < 16; ++t) {
    const u16* As_ = Asb[t & 1];
    const u16* Bs_ = Bsb[t & 1];
    // phase 0: read ALL frags (both kc), MFMA kc0
    bf16x8 a0[4], b0f[4], a1[4], b1f[4];
#pragma unroll
    for (int i = 0; i < 4; ++i) {
      a0[i]  = *lds_frag(As_, wy * 64 + i * 16 + r16, lg);
      b0f[i] = *lds_frag(Bs_, wx * 64 + i * 16 + r16, lg);
      a1[i]  = *lds_frag(As_, wy * 64 + i * 16 + r16, 4 + lg);
      b1f[i] = *lds_frag(Bs_, wx * 64 + i * 16 + r16, 4 + lg);
    }
    __builtin_amdgcn_s_setprio(1);
#pragma unroll
    for (int i = 0; i < 4; ++i)
#pragma unroll
      for (int j = 0; j < 4; ++j)
        acc[i][j] = __builtin_amdgcn_mfma_f32_16x16x32_bf16(a0[i], b0f[j], acc[i][j], 0, 0, 0);
    __builtin_amdgcn_s_setprio(0);
    LGKM0;      // all my ds_reads (incl. kc1) landed in regs
    BARRIER;    // => every wave done reading buf[t&1]; safe to overwrite below
    // phase 1: stage tile t+2 into buf[t&1]; MFMA kc1
    int nx = t + 2;
    if (nx < 16) {
      int e = (nx >> 3) ? eB : eA;
      int ks = nx & 7;
      STAGE_A(Asb[t & 1], ks);
      STAGE_B(Bsb[t & 1], e, ks);
    }
    __builtin_amdgcn_s_setprio(1);
#pragma unroll
    for (int i = 0; i < 4; ++i)
#pragma unroll
      for (int j = 0; j < 4; ++j)
        acc[i][j] = __builtin_amdgcn_mfma_f32_16x16x32_bf16(a1[i], b1f[j], acc[i][j], 0, 0, 0);
    __builtin_amdgcn_s_setprio(0);
    // boundary: tile t+1 ready (its 8 loads are older than t+2's 8 in flight)
    if (t < 14) { VMCNT(8); BARRIER; }
    else if (t == 14) { VMCNT(0); BARRIER; }
    // per-expert epilogue after expert A's last tile
    if (t == 7) {
#pragma unroll
      for (int i = 0; i < 4; ++i) {
        int lrb = wy * 64 + i * 16 + lg * 4;
        float wv[4];
#pragma unroll
        for (int rr = 0; rr < 4; ++rr) wv[rr] = wpair[m0 + lrb + rr].x;
#pragma unroll
        for (int j = 0; j < 4; ++j) {
          int h = n0 + wx * 64 + j * 16 + r16;
          float bias = ebias[eA * DIM + h];
#pragma unroll
          for (int rr = 0; rr < 4; ++rr) {
            float z = acc[i][j][rr] + bias;
            float sg = 1.0f / (1.0f + __expf(-z));
            comba[i][j][rr] = wv[rr] * (z * sg);
            acc[i][j][rr] = 0.0f;
          }
        }
      }
    }
  }
  // final epilogue: expert B fold + scatter C-write (pad rows masked)
#pragma unroll
  for (int i = 0; i < 4; ++i) {
    int lrb = wy * 64 + i * 16 + lg * 4;
    float wv[4];
    int idw[4];
#pragma unroll
    for (int rr = 0; rr < 4; ++rr) {
      wv[rr] = wpair[m0 + lrb + rr].y;
      idw[rr] = list[m0 + lrb + rr];
    }
#pragma unroll
    for (int j = 0; j < 4; ++j) {
      int h = n0 + wx * 64 + j * 16 + r16;
      float bias = ebias[eB * DIM + h];
#pragma unroll
      for (int rr = 0; rr < 4; ++rr) {
        float z = acc[i][j][rr] + bias;
        float sg = 1.0f / (1.0f + __expf(-z));
        float v = comba[i][j][rr] + wv[rr] * (z * sg);
        if (idw[rr] >= 0) comb[(size_t)idw[rr] * DIM + h] = f2bf(v);
      }
    }
  }
#undef STAGE_A
#undef STAGE_B
}

// ---------------- K4: fused out-proj + bias + residual + RMSNorm ----------------
// BM=64 tokens/block, full N=512. 8 waves = 8 col-strips of 64. A (comb) via
// swizzled LDS 2-deep prefetch; B (out_w, L2-hot) register-prefetched 1 ahead.
__global__ __launch_bounds__(512, 2) void outnorm(
    const u16* __restrict__ comb, const u16* __restrict__ owt,
    const float* __restrict__ ob, const float* __restrict__ x,
    const float* __restrict__ nw, float* __restrict__ out) {
  __shared__ u16 As[2][64 * 64];    // 16 KB
  __shared__ float rowsum[64][8];
  int tid = threadIdx.x, lane = tid & 63, w = tid >> 6;  // 8 waves
  int m0 = blockIdx.x * 64;
  int r16 = lane & 15, lg = lane >> 4;
  int rl = lane >> 3;
  int scb = ((lane & 7) ^ rl) * 8;
  int w64 = w * 64;

  f32x4 acc[4][4];
#pragma unroll
  for (int i = 0; i < 4; ++i)
#pragma unroll
    for (int j = 0; j < 4; ++j) acc[i][j] = (f32x4)(0.f);

#define OSTAGE(buf, ks)                                                        \
  GLOAD_LDS16(comb + (size_t)(m0 + w * 8 + rl) * DIM + (ks) * 64 + scb,        \
              (buf) + (w * 8) * 64)
#define LOADB(arr, T)                                                          \
  _Pragma("unroll") for (int j = 0; j < 4; ++j)                                \
    _Pragma("unroll") for (int kc = 0; kc < 2; ++kc)                           \
      arr[j * 2 + kc] = *(const bf16x8*)(owt + (size_t)(w64 + j * 16 + r16) * DIM + \
                                         (T) * 64 + kc * 32 + lg * 8);

  bf16x8 bA[8], bB[8];
  OSTAGE(As[0], 0);
  OSTAGE(As[1], 1);
  LOADB(bA, 0);
  VMCNT(0);
  BARRIER;

#define OTILE(T, CUR, BCUR, BNXT)                                              \
  {                                                                            \
    bf16x8 af[8];                                                              \
    _Pragma("unroll") for (int i = 0; i < 4; ++i) {                            \
      af[i]     = *lds_frag(As[CUR], i * 16 + r16, lg);                        \
      af[4 + i] = *lds_frag(As[CUR], i * 16 + r16, 4 + lg);                    \
    }                                                                          \
    __builtin_amdgcn_s_setprio(1);                                             \
    _Pragma("unroll") for (int i = 0; i < 4; ++i)                              \
      _Pragma("unroll") for (int j = 0; j < 4; ++j)                            \
        acc[i][j] = __builtin_amdgcn_mfma_f32_16x16x32_bf16(af[i], BCUR[j * 2], acc[i][j], 0, 0, 0); \
    __builtin_amdgcn_s_setprio(0);                                             \
    LGKM0;                                                                     \
    BARRIER;                                                                   \
    if ((T) + 1 < 8) { LOADB(BNXT, (T) + 1); }                                 \
    if ((T) + 2 < 8) { OSTAGE(As[CUR], (T) + 2); }                             \
    __builtin_amdgcn_s_setprio(1);                                             \
    _Pragma("unroll") for (int i = 0; i < 4; ++i)                              \
      _Pragma("unroll") for (int j = 0; j < 4; ++j)                            \
        acc[i][j] = __builtin_amdgcn_mfma_f32_16x16x32_bf16(af[4 + i], BCUR[j * 2 + 1], acc[i][j], 0, 0, 0); \
    __builtin_amdgcn_s_setprio(0);                                             \
    if ((T) < 6) { VMCNT(9); BARRIER; }                                        \
    else if ((T) == 6) { VMCNT(8); BARRIER; }                                  \
  }

  OTILE(0, 0, bA, bB)
  OTILE(1, 1, bB, bA)
  OTILE(2, 0, bA, bB)
  OTILE(3, 1, bB, bA)
  OTILE(4, 0, bA, bB)
  OTILE(5, 1, bB, bA)
  OTILE(6, 0, bA, bB)
  OTILE(7, 1, bB, bA)
#undef OTILE
#undef OSTAGE
#undef LOADB

  // epilogue: y = x + out + bias; rowsum(y^2) across 16 lanes then 8 waves
  float part[4][4];
#pragma unroll
  for (int i = 0; i < 4; ++i)
#pragma unroll
    for (int rr = 0; rr < 4; ++rr) part[i][rr] = 0.f;
#pragma unroll
  for (int i = 0; i < 4; ++i) {
#pragma unroll
    for (int j = 0; j < 4; ++j) {
      int h = w64 + j * 16 + r16;
      float bias = ob[h];
#pragma unroll
      for (int rr = 0; rr < 4; ++rr) {
        int lr = i * 16 + lg * 4 + rr;
        float yv = x[(size_t)(m0 + lr) * DIM + h] + acc[i][j][rr] + bias;
        acc[i][j][rr] = yv;
        part[i][rr] += yv * yv;
      }
    }
  }
#pragma unroll
  for (int off = 1; off < 16; off <<= 1)
#pragma unroll
    for (int i = 0; i < 4; ++i)
#pragma unroll
      for (int rr = 0; rr < 4; ++rr) part[i][rr] += __shfl_xor(part[i][rr], off);
  if (r16 == 0) {
#pragma unroll
    for (int i = 0; i < 4; ++i)
#pragma unroll
      for (int rr = 0; rr < 4; ++rr)
        rowsum[i * 16 + lg * 4 + rr][w] = part[i][rr];
  }
  __syncthreads();
  float inv[4][4];
#pragma unroll
  for (int i = 0; i < 4; ++i)
#pragma unroll
    for (int rr = 0; rr < 4; ++rr) {
      int lr = i * 16 + lg * 4 + rr;
      float s = 0.f;
#pragma unroll
      for (int q = 0; q < 8; ++q) s += rowsum[lr][q];
      inv[i][rr] = 1.0f / sqrtf(s * (1.0f / 512.0f) + 1e-6f);
    }
#pragma unroll
  for (int i = 0; i < 4; ++i) {
#pragma unroll
    for (int j = 0; j < 4; ++j) {
      int h = w64 + j * 16 + r16;
      float wv = nw[h];
#pragma unroll
      for (int rr = 0; rr < 4; ++rr) {
        int lr = i * 16 + lg * 4 + rr;
        out[(size_t)(m0 + lr) * DIM + h] = acc[i][j][rr] * inv[i][rr] * wv;
      }
    }
  }
}

extern "C" void kernel_launch(void* const* d_in, const int* in_sizes, int n_in,
                              void* d_out, int out_size, void* d_ws, size_t ws_size,
                              hipStream_t stream) {
  const float* x  = (const float*)d_in[0];
  const float* rw = (const float*)d_in[1];
  const float* rb = (const float*)d_in[2];
  const float* ew = (const float*)d_in[3];
  const float* eb = (const float*)d_in[4];
  const float* ow = (const float*)d_in[5];
  const float* ob = (const float*)d_in[6];
  const float* nw = (const float*)d_in[7];
  float* out = (float*)d_out;

  char* ws = (char*)d_ws;
  u16*   xb    = (u16*)(ws);                        // 64 MiB  x as bf16
  u16*   combb = (u16*)(ws + 67108864);             // 64 MiB  combined expert out (bf16)
  int*   pp    = (int*)(ws + 67108864);             // aliases combb (dead before it's written)
  float2* wab  = (float2*)(ws + 67108864 + 262144);
  u16*   ewt   = (u16*)(ws + 134217728);            // 2 MiB   expert_w^T bf16
  u16*   owt   = (u16*)(ws + 136314880);            // 0.5 MiB out_w^T bf16
  int*   list  = (int*)(ws + 136839168);            // 336 KiB [6][REG] token ids
  float2* wpair = (float2*)(ws + 136839168 + 344064); // 672 KiB [6][REG] weights
  int*   cnt   = (int*)(ws + 136839168 + 344064 + 688128); // 24 B group counts

  hipMemsetAsync(cnt, 0, 24, stream);
  hipMemsetAsync(list, 0xFF, 6 * REG * 4, stream);
  wconv<<<dim3(256, 4), 256, 0, stream>>>(ew, ewt);
  wconv<<<dim3(256, 1), 256, 0, stream>>>(ow, owt);
  router_kernel<<<NTOK / 4, 256, 0, stream>>>(x, rw, rb, xb, pp, wab);
  assignscatter<<<NTOK / 256, 256, 0, stream>>>(pp, wab, cnt, list, wpair);
  expert_gemm<<<dim3(6 * REG / 128 * 4), 256, 0, stream>>>(xb, ewt, eb, cnt, list, wpair, combb);
  outnorm<<<dim3(NTOK / 64), 512, 0, stream>>>(combb, owt, ob, x, nw, out);
}

// Round 5
// 369.748 us; speedup vs baseline: 1.3255x; 1.0753x over previous
//
#include <hip/hip_runtime.h>
#include <hip/hip_bf16.h>
#include <stdint.h>

#define NTOK 65536
#define DIM 512
#define NEXP 4
#define REG 14336  // per-pair-group slot region (expected ~10923; 112 blocks of 128)

using u16 = unsigned short;
using u32 = unsigned int;
typedef __attribute__((ext_vector_type(4))) float f32x4;
typedef __attribute__((ext_vector_type(8))) short bf16x8;
typedef __attribute__((ext_vector_type(8))) u16 u16x8;

__device__ __forceinline__ u16 f2bf(float f) {
  u32 u = __builtin_bit_cast(u32, f);
  u32 r = (u + 0x7FFFu + ((u >> 16) & 1u)) >> 16;
  return (u16)r;
}

#define GLOAD_LDS16(gp, lp)                                                    \
  __builtin_amdgcn_global_load_lds(                                            \
      (const __attribute__((address_space(1))) void*)(gp),                     \
      (__attribute__((address_space(3))) void*)(lp), 16, 0, 0)

#define FENCE asm volatile("" ::: "memory")
#define BARRIER { FENCE; __builtin_amdgcn_s_barrier(); FENCE; }
#define LGKM0 { asm volatile("s_waitcnt lgkmcnt(0)" ::: "memory"); __builtin_amdgcn_sched_barrier(0); }
#define VMCNT_(n) asm volatile("s_waitcnt vmcnt(" #n ")" ::: "memory")
#define VMCNT(n) VMCNT_(n)

// 128B-row LDS (outnorm): logical (row, 16B-chunk 0..7) -> phys chunk = c ^ (row&7)
__device__ __forceinline__ const bf16x8* lds_frag(const u16* base, int row, int chunk) {
  return (const bf16x8*)((const char*)base + row * 128 + (((chunk) ^ (row & 7)) << 4));
}
// 64B-row LDS (expert, BK=32): logical chunk c (0..3) lives at phys (c + rot(row))&3,
// rot = ((row&15)>>1)&3. rchByte = precomputed phys byte offset for this lane.
__device__ __forceinline__ const bf16x8* frag32(const u16* base, int row, int rchByte) {
  return (const bf16x8*)((const char*)base + row * 64 + rchByte);
}

// ---------------- K0: weight transpose + fp32->bf16 (both mats) + cnt zero ----------------
__global__ void wconv(const float* __restrict__ ew, const float* __restrict__ ow,
                      u16* __restrict__ ewt, u16* __restrict__ owt, int* __restrict__ cnt) {
  __shared__ float tile[32][33];
  int mat = blockIdx.y;
  if (blockIdx.x == 0 && mat == 0 && threadIdx.x < 6) cnt[threadIdx.x] = 0;
  const float* s = (mat < 4) ? ew + (size_t)mat * DIM * DIM : ow;
  u16* d = (mat < 4) ? ewt + (size_t)mat * DIM * DIM : owt;
  int tx = blockIdx.x & 15, ty = blockIdx.x >> 4;
  int lx = threadIdx.x & 31, ly0 = threadIdx.x >> 5;
#pragma unroll
  for (int i = 0; i < 4; ++i) {
    int ly = ly0 + i * 8;
    tile[ly][lx] = s[(size_t)(ty * 32 + ly) * DIM + tx * 32 + lx];
  }
  __syncthreads();
#pragma unroll
  for (int i = 0; i < 4; ++i) {
    int ly = ly0 + i * 8;
    d[(size_t)(tx * 32 + ly) * DIM + ty * 32 + lx] = f2bf(tile[lx][ly]);
  }
}

// ---------------- K1: router (fp32) + x -> bf16 ----------------
__global__ void router_kernel(const float* __restrict__ x, const float* __restrict__ rw,
                              const float* __restrict__ rb, u16* __restrict__ xb,
                              int* __restrict__ pp, float2* __restrict__ wab) {
  int lane = threadIdx.x & 63, wave = threadIdx.x >> 6;
  size_t t = (size_t)blockIdx.x * 4 + wave;
  const float* xr = x + t * DIM + lane * 8;
  f32x4 v0 = *(const f32x4*)xr;
  f32x4 v1 = *(const f32x4*)(xr + 4);
  float l0 = 0.f, l1 = 0.f, l2 = 0.f, l3 = 0.f;
  const float* rwp = rw + (size_t)lane * 32;
#pragma unroll
  for (int j = 0; j < 8; ++j) {
    float xv = (j < 4) ? v0[j] : v1[j - 4];
    f32x4 r = *(const f32x4*)(rwp + j * 4);
    l0 += xv * r[0]; l1 += xv * r[1]; l2 += xv * r[2]; l3 += xv * r[3];
  }
#pragma unroll
  for (int off = 32; off; off >>= 1) {
    l0 += __shfl_xor(l0, off); l1 += __shfl_xor(l1, off);
    l2 += __shfl_xor(l2, off); l3 += __shfl_xor(l3, off);
  }
  float lv[4] = {l0 + rb[0], l1 + rb[1], l2 + rb[2], l3 + rb[3]};
  int i0 = 0; float b0 = lv[0];
#pragma unroll
  for (int e = 1; e < 4; ++e) if (lv[e] > b0) { b0 = lv[e]; i0 = e; }
  int i1 = (i0 == 0) ? 1 : 0; float b1 = lv[i1];
#pragma unroll
  for (int e = 0; e < 4; ++e) if (e != i0 && lv[e] > b1) { b1 = lv[e]; i1 = e; }
  float ex = __expf(b1 - b0);
  float w0 = 1.0f / (1.0f + ex);
  float w1 = ex * w0;
  if (lane == 0) {
    int a = (i0 < i1) ? i0 : i1;
    int b = (i0 < i1) ? i1 : i0;
    const int ptab[16] = {-1, 0, 1, 2, -1, -1, 3, 4, -1, -1, -1, 5, -1, -1, -1, -1};
    pp[t] = ptab[a * 4 + b];
    float wa = (a == i0) ? w0 : w1;
    float wb = (a == i0) ? w1 : w0;
    wab[t] = make_float2(wa, wb);
  }
  u16x8 o;
#pragma unroll
  for (int j = 0; j < 4; ++j) { o[j] = f2bf(v0[j]); o[4 + j] = f2bf(v1[j]); }
  *(u16x8*)(xb + t * DIM + lane * 8) = o;
}

// ---------------- K2: wave-aggregated group assignment + scatter ----------------
__global__ void assignscatter(const int* __restrict__ pp, const float2* __restrict__ wab,
                              int* __restrict__ cnt, int* __restrict__ list,
                              float2* __restrict__ wpair) {
  int t = blockIdx.x * 256 + threadIdx.x;
  int lane = threadIdx.x & 63;
  int p = pp[t];
  float2 w = wab[t];
  int pos = 0;
#pragma unroll
  for (int q = 0; q < 6; ++q) {
    unsigned long long m = __ballot(p == q);
    if (p == q) {
      int rank = __popcll(m & ((1ull << lane) - 1ull));
      int leader = __ffsll((long long)m) - 1;
      int base = 0;
      if (lane == leader) base = atomicAdd(&cnt[q], (int)__popcll(m));
      base = __shfl(base, leader);
      pos = base + rank;
    }
  }
  int slot = p * REG + pos;
  if (pos < REG) {
    list[slot] = t;
    wpair[slot] = w;
  }
}

// ---------------- K3: sparse expert GEMM, expert-inner dual-acc ----------------
// 128x128 tile, 4 waves, 16 K-steps of BK=32. Per step: stage A + B_eA + B_eB
// (6 gloads/wave), 12 ds_reads, 32 MFMA into accA/accB. 3-deep prefetch,
// counted vmcnt(12), rotation-swizzled 64B-row LDS.
__global__ __launch_bounds__(256, 2) void expert_gemm(
    const u16* __restrict__ xb, const u16* __restrict__ ewt,
    const float* __restrict__ ebias, const int* __restrict__ cnt,
    const int* __restrict__ list, const float2* __restrict__ wpair,
    u16* __restrict__ comb) {
  __shared__ u16 Asl[3][128 * 32];
  __shared__ u16 Bal[3][128 * 32];
  __shared__ u16 Bbl[3][128 * 32];
  int tid = threadIdx.x, lane = tid & 63, wave = tid >> 6;
  int wy = wave >> 1, wx = wave & 1;
  // XCD swizzle: the 4 n-blocks of one M-panel -> same XCD, adjacent dispatch
  int b = blockIdx.x;
  int chunk = b >> 5, within = b & 31;
  int panel = chunk * 8 + (within & 7);  // 0..671 (bijective: 2688 % 32 == 0)
  int nblk = within >> 3;                // 0..3
  int p = panel / (REG / 128);
  int m0 = panel * 128;
  int cntp = cnt[p];
  if (m0 - p * REG >= cntp) return;
  int n0 = nblk * 128;
  const int ea2[6] = {0, 0, 0, 1, 1, 2};
  const int eb2[6] = {1, 2, 3, 2, 3, 3};
  int eA = ea2[p], eB = eb2[p];

  // staging lane geometry (16 rows x 4 chunks of 16B per gload instr)
  int r4 = lane >> 2, c4 = lane & 3;
  int rot = (r4 >> 1) & 3;
  int kch = ((c4 - rot) & 3) * 8;  // logical k-elem offset within BK=32
  // read lane geometry
  int r16 = lane & 15, lg = lane >> 4;
  int rchB = (((lg + ((r16 >> 1) & 3)) & 3)) * 16;  // phys byte chunk

  int sid2[2];
#pragma unroll
  for (int j = 0; j < 2; ++j) {
    int slot = m0 + wave * 32 + j * 16 + r4;
    int idv = list[slot];
    sid2[j] = ((slot - p * REG) < cntp) ? idv : 0;
  }

  f32x4 accA[4][4], accB[4][4];
#pragma unroll
  for (int i = 0; i < 4; ++i)
#pragma unroll
    for (int j = 0; j < 4; ++j) { accA[i][j] = (f32x4)(0.f); accB[i][j] = (f32x4)(0.f); }

#define STAGE(bi, ks)                                                          \
  do {                                                                         \
    _Pragma("unroll") for (int j = 0; j < 2; ++j) {                            \
      GLOAD_LDS16(xb + (size_t)sid2[j] * DIM + (ks) * 32 + kch,                \
                  Asl[bi] + (wave * 32 + j * 16) * 32);                        \
    }                                                                          \
    _Pragma("unroll") for (int j = 0; j < 2; ++j) {                            \
      int hr = n0 + wave * 32 + j * 16 + r4;                                   \
      GLOAD_LDS16(ewt + (size_t)eA * DIM * DIM + (size_t)hr * DIM + (ks) * 32 + kch, \
                  Bal[bi] + (wave * 32 + j * 16) * 32);                        \
      GLOAD_LDS16(ewt + (size_t)eB * DIM * DIM + (size_t)hr * DIM + (ks) * 32 + kch, \
                  Bbl[bi] + (wave * 32 + j * 16) * 32);                        \
    }                                                                          \
  } while (0)

  STAGE(0, 0); STAGE(1, 1); STAGE(2, 2);
  VMCNT(12);
  BARRIER;

  int cur = 0;
#pragma unroll 1
  for (int t = 0; t < 16; ++t) {
    const u16* As_ = Asl[cur];
    const u16* Ba_ = Bal[cur];
    const u16* Bb_ = Bbl[cur];
    bf16x8 a[4], ba[4], bb[4];
#pragma unroll
    for (int i = 0; i < 4; ++i) {
      a[i]  = *frag32(As_, wy * 64 + i * 16 + r16, rchB);
      ba[i] = *frag32(Ba_, wx * 64 + i * 16 + r16, rchB);
      bb[i] = *frag32(Bb_, wx * 64 + i * 16 + r16, rchB);
    }
    __builtin_amdgcn_s_setprio(1);
#pragma unroll
    for (int i = 0; i < 4; ++i)
#pragma unroll
      for (int j = 0; j < 4; ++j)
        accA[i][j] = __builtin_amdgcn_mfma_f32_16x16x32_bf16(a[i], ba[j], accA[i][j], 0, 0, 0);
    __builtin_amdgcn_s_setprio(0);
    LGKM0;      // my 12 ds_reads landed (incl. bb)
    BARRIER;    // block-wide: buf[cur] fully consumed -> safe to overwrite
    if (t + 3 < 16) STAGE(cur, t + 3);
    __builtin_amdgcn_s_setprio(1);
#pragma unroll
    for (int i = 0; i < 4; ++i)
#pragma unroll
      for (int j = 0; j < 4; ++j)
        accB[i][j] = __builtin_amdgcn_mfma_f32_16x16x32_bf16(a[i], bb[j], accB[i][j], 0, 0, 0);
    __builtin_amdgcn_s_setprio(0);
    // boundary: tile t+1 must be resident; keep later prefetches in flight
    if (t < 13) { VMCNT(12); BARRIER; }
    else if (t == 13) { VMCNT(6); BARRIER; }
    else if (t == 14) { VMCNT(0); BARRIER; }
    cur = (cur == 2) ? 0 : cur + 1;
  }
#undef STAGE

  // epilogue: bias + SiLU per expert, weighted combine, scatter by token id
  float bA4[4], bB4[4];
#pragma unroll
  for (int j = 0; j < 4; ++j) {
    int h = n0 + wx * 64 + j * 16 + r16;
    bA4[j] = ebias[eA * DIM + h];
    bB4[j] = ebias[eB * DIM + h];
  }
#pragma unroll
  for (int i = 0; i < 4; ++i) {
    int rb = wy * 64 + i * 16 + lg * 4;
#pragma unroll
    for (int rr = 0; rr < 4; ++rr) {
      int slot = m0 + rb + rr;
      bool val = (slot - p * REG) < cntp;
      int id = list[slot];
      float2 wv = wpair[slot];
#pragma unroll
      for (int j = 0; j < 4; ++j) {
        float zA = accA[i][j][rr] + bA4[j];
        float zB = accB[i][j][rr] + bB4[j];
        float sA = zA / (1.0f + __expf(-zA));
        float sB = zB / (1.0f + __expf(-zB));
        float v = wv.x * sA + wv.y * sB;
        if (val) {
          int h = n0 + wx * 64 + j * 16 + r16;
          comb[(size_t)id * DIM + h] = f2bf(v);
        }
      }
    }
  }
}

// ---------------- K4: fused out-proj + bias + residual + RMSNorm ----------------
// 256 threads (4 waves), BM=64 tokens, full N=512; wave w owns cols w*128..+127.
// A (comb) via swizzled LDS dbuf; B (out_w, L2-hot) kc-split register loads.
__global__ __launch_bounds__(256, 2) void outnorm(
    const u16* __restrict__ comb, const u16* __restrict__ owt,
    const float* __restrict__ ob, const float* __restrict__ x,
    const float* __restrict__ nw, float* __restrict__ out) {
  __shared__ u16 As[2][64 * 64];   // 16 KB
  __shared__ float rowsum[64][4];
  int tid = threadIdx.x, lane = tid & 63, w = tid >> 6;  // 4 waves
  int m0 = blockIdx.x * 64;
  int r16 = lane & 15, lg = lane >> 4;
  int rl = lane >> 3;
  int scb = ((lane & 7) ^ rl) * 8;
  int n0w = w * 128;

  f32x4 acc[4][8];
#pragma unroll
  for (int i = 0; i < 4; ++i)
#pragma unroll
    for (int j = 0; j < 8; ++j) acc[i][j] = (f32x4)(0.f);

#define OSTG(bi, ks)                                                           \
  _Pragma("unroll") for (int j = 0; j < 2; ++j) {                              \
    GLOAD_LDS16(comb + (size_t)(m0 + w * 16 + j * 8 + rl) * DIM + (ks) * 64 + scb, \
                As[bi] + (w * 16 + j * 8) * 64);                               \
  }

  OSTG(0, 0);
  __syncthreads();
#pragma unroll 1
  for (int t = 0; t < 8; ++t) {
    if (t + 1 < 8) OSTG((t + 1) & 1, t + 1);
    const u16* Ab = As[t & 1];
    bf16x8 af[8];
#pragma unroll
    for (int i = 0; i < 4; ++i) {
      af[i * 2]     = *lds_frag(Ab, i * 16 + r16, lg);
      af[i * 2 + 1] = *lds_frag(Ab, i * 16 + r16, 4 + lg);
    }
#pragma unroll
    for (int kc = 0; kc < 2; ++kc) {
      bf16x8 bfr[8];
#pragma unroll
      for (int j = 0; j < 8; ++j)
        bfr[j] = *(const bf16x8*)(owt + (size_t)(n0w + j * 16 + r16) * DIM +
                                  t * 64 + kc * 32 + lg * 8);
      __builtin_amdgcn_s_setprio(1);
#pragma unroll
      for (int i = 0; i < 4; ++i)
#pragma unroll
        for (int j = 0; j < 8; ++j)
          acc[i][j] = __builtin_amdgcn_mfma_f32_16x16x32_bf16(af[i * 2 + kc], bfr[j], acc[i][j], 0, 0, 0);
      __builtin_amdgcn_s_setprio(0);
    }
    __syncthreads();
  }
#undef OSTG

  // epilogue: y = x + out + bias; rowsum(y^2); RMSNorm write
  float part[4][4];
#pragma unroll
  for (int i = 0; i < 4; ++i)
#pragma unroll
    for (int rr = 0; rr < 4; ++rr) part[i][rr] = 0.f;
#pragma unroll
  for (int i = 0; i < 4; ++i) {
#pragma unroll
    for (int j = 0; j < 8; ++j) {
      int h = n0w + j * 16 + r16;
      float bias = ob[h];
#pragma unroll
      for (int rr = 0; rr < 4; ++rr) {
        int lr = i * 16 + lg * 4 + rr;
        float yv = x[(size_t)(m0 + lr) * DIM + h] + acc[i][j][rr] + bias;
        acc[i][j][rr] = yv;
        part[i][rr] += yv * yv;
      }
    }
  }
#pragma unroll
  for (int off = 1; off < 16; off <<= 1)
#pragma unroll
    for (int i = 0; i < 4; ++i)
#pragma unroll
      for (int rr = 0; rr < 4; ++rr) part[i][rr] += __shfl_xor(part[i][rr], off);
  if (r16 == 0) {
#pragma unroll
    for (int i = 0; i < 4; ++i)
#pragma unroll
      for (int rr = 0; rr < 4; ++rr)
        rowsum[i * 16 + lg * 4 + rr][w] = part[i][rr];
  }
  __syncthreads();
  float inv[4][4];
#pragma unroll
  for (int i = 0; i < 4; ++i)
#pragma unroll
    for (int rr = 0; rr < 4; ++rr) {
      int lr = i * 16 + lg * 4 + rr;
      float s = rowsum[lr][0] + rowsum[lr][1] + rowsum[lr][2] + rowsum[lr][3];
      inv[i][rr] = 1.0f / sqrtf(s * (1.0f / 512.0f) + 1e-6f);
    }
#pragma unroll
  for (int i = 0; i < 4; ++i) {
#pragma unroll
    for (int j = 0; j < 8; ++j) {
      int h = n0w + j * 16 + r16;
      float wv = nw[h];
#pragma unroll
      for (int rr = 0; rr < 4; ++rr) {
        int lr = i * 16 + lg * 4 + rr;
        out[(size_t)(m0 + lr) * DIM + h] = acc[i][j][rr] * inv[i][rr] * wv;
      }
    }
  }
}

extern "C" void kernel_launch(void* const* d_in, const int* in_sizes, int n_in,
                              void* d_out, int out_size, void* d_ws, size_t ws_size,
                              hipStream_t stream) {
  const float* x  = (const float*)d_in[0];
  const float* rw = (const float*)d_in[1];
  const float* rb = (const float*)d_in[2];
  const float* ew = (const float*)d_in[3];
  const float* eb = (const float*)d_in[4];
  const float* ow = (const float*)d_in[5];
  const float* ob = (const float*)d_in[6];
  const float* nw = (const float*)d_in[7];
  float* out = (float*)d_out;

  char* ws = (char*)d_ws;
  u16*   xb    = (u16*)(ws);                        // 64 MiB  x as bf16
  u16*   combb = (u16*)(ws + 67108864);             // 64 MiB  combined expert out (bf16)
  int*   pp    = (int*)(ws + 67108864);             // aliases combb (dead before it's written)
  float2* wab  = (float2*)(ws + 67108864 + 262144);
  u16*   ewt   = (u16*)(ws + 134217728);            // 2 MiB   expert_w^T bf16
  u16*   owt   = (u16*)(ws + 136314880);            // 0.5 MiB out_w^T bf16
  int*   list  = (int*)(ws + 136839168);            // 336 KiB [6][REG] token ids
  float2* wpair = (float2*)(ws + 136839168 + 344064); // 672 KiB [6][REG] weights
  int*   cnt   = (int*)(ws + 136839168 + 344064 + 688128); // 24 B group counts

  wconv<<<dim3(256, 5), 256, 0, stream>>>(ew, ow, ewt, owt, cnt);
  router_kernel<<<NTOK / 4, 256, 0, stream>>>(x, rw, rb, xb, pp, wab);
  assignscatter<<<NTOK / 256, 256, 0, stream>>>(pp, wab, cnt, list, wpair);
  expert_gemm<<<dim3(6 * REG / 128 * 4), 256, 0, stream>>>(xb, ewt, eb, cnt, list, wpair, combb);
  outnorm<<<dim3(NTOK / 64), 256, 0, stream>>>(combb, owt, ob, x, nw, out);
}